// Round 2
// baseline (4316.127 us; speedup 1.0000x reference)
//
#include <hip/hip_runtime.h>

// Problem constants (from reference setup_inputs)
#define BATCH 4
#define NNODE 50000
#define NEDGE 1600000
#define F_IN 12
#define F_OUT 48
#define SEQ 12
#define DOUT 4   // F_OUT / SEQ

// Workspace layout (floats):
//   deg/dinv : BATCH*NNODE              (200,000)
//   aggx     : BATCH*NNODE*F_IN         (2,400,000)
// total 10.4 MB < ws_size

// Hardware f32 atomic add (global_atomic_add_f32), not a CAS loop.
// d_ws is coarse-grained device memory, so this is safe.
__device__ __forceinline__ void fadd(float* p, float v) {
    unsafeAtomicAdd(p, v);
}

__global__ void __launch_bounds__(256) k_init(float* __restrict__ deg,
                                              float* __restrict__ aggx) {
    int i = blockIdx.x * 256 + threadIdx.x;
    if (i < BATCH * NNODE) deg[i] = 1.0f;            // self-loop weight
    if (i < BATCH * NNODE * F_IN) aggx[i] = 0.0f;
}

__global__ void __launch_bounds__(256) k_deg(const int* __restrict__ ei,
                                             const float* __restrict__ ew,
                                             float* __restrict__ deg) {
    int e = blockIdx.x * 256 + threadIdx.x;
    int b = blockIdx.y;
    if (e >= NEDGE) return;
    int dst = ei[((size_t)b * 2 + 1) * NEDGE + e];
    float w = ew[(size_t)b * NEDGE + e];
    fadd(deg + b * NNODE + dst, w);
}

__global__ void __launch_bounds__(256) k_rsqrt(float* __restrict__ deg) {
    int i = blockIdx.x * 256 + threadIdx.x;
    if (i < BATCH * NNODE) deg[i] = rsqrtf(deg[i]);
}

// Aggregate in F_IN space (4x fewer atomics than F_OUT space; W applied later).
__global__ void __launch_bounds__(256) k_scatter(const int* __restrict__ ei,
                                                 const float* __restrict__ ew,
                                                 const float* __restrict__ x,
                                                 const float* __restrict__ dinv,
                                                 float* __restrict__ aggx) {
    int e = blockIdx.x * 256 + threadIdx.x;
    int b = blockIdx.y;
    if (e >= NEDGE) return;
    const size_t ebase = (size_t)b * 2 * NEDGE;
    int src = ei[ebase + e];
    int dst = ei[ebase + NEDGE + e];
    float w = ew[(size_t)b * NEDGE + e];
    float norm = dinv[b * NNODE + src] * w * dinv[b * NNODE + dst];

    // x row: 12 floats = 48 bytes, 16B-aligned -> 3x float4
    const float4* xr = (const float4*)(x + ((size_t)b * NNODE + src) * F_IN);
    float4 v0 = xr[0], v1 = xr[1], v2 = xr[2];
    float* ar = aggx + ((size_t)b * NNODE + dst) * F_IN;
    fadd(ar + 0,  v0.x * norm);
    fadd(ar + 1,  v0.y * norm);
    fadd(ar + 2,  v0.z * norm);
    fadd(ar + 3,  v0.w * norm);
    fadd(ar + 4,  v1.x * norm);
    fadd(ar + 5,  v1.y * norm);
    fadd(ar + 6,  v1.z * norm);
    fadd(ar + 7,  v1.w * norm);
    fadd(ar + 8,  v2.x * norm);
    fadd(ar + 9,  v2.y * norm);
    fadd(ar + 10, v2.z * norm);
    fadd(ar + 11, v2.w * norm);
}

// Per node: add self-loop term, apply W (12x48) + bias, write transposed
// output out[b][s][n][0..4) as float4 (coalesced over n).
__global__ void __launch_bounds__(256) k_final(const float* __restrict__ aggx,
                                               const float* __restrict__ x,
                                               const float* __restrict__ dinv,
                                               const float* __restrict__ Wm,
                                               const float* __restrict__ bias,
                                               float* __restrict__ out) {
    __shared__ float sW[F_IN * F_OUT];
    __shared__ float sb[F_OUT];
    int t = threadIdx.x;
    for (int i = t; i < F_IN * F_OUT; i += 256) sW[i] = Wm[i];
    if (t < F_OUT) sb[t] = bias[t];
    __syncthreads();

    int i = blockIdx.x * 256 + t;
    if (i >= BATCH * NNODE) return;
    int b = i / NNODE;
    int n = i - b * NNODE;

    float di = dinv[i];
    float self = di * di;

    float a[F_IN];
    const float* ar = aggx + (size_t)i * F_IN;
    const float* xr = x + (size_t)i * F_IN;
#pragma unroll
    for (int k = 0; k < F_IN; k++) a[k] = ar[k] + xr[k] * self;

    float h[F_OUT];
#pragma unroll
    for (int j = 0; j < F_OUT; j++) {
        float acc = sb[j];
#pragma unroll
        for (int k = 0; k < F_IN; k++) acc = fmaf(a[k], sW[k * F_OUT + j], acc);
        h[j] = acc;
    }

    float4* out4 = (float4*)out;
#pragma unroll
    for (int s = 0; s < SEQ; s++) {
        float4 v = make_float4(h[s * 4 + 0], h[s * 4 + 1], h[s * 4 + 2], h[s * 4 + 3]);
        out4[(size_t)(b * SEQ + s) * NNODE + n] = v;
    }
}

extern "C" void kernel_launch(void* const* d_in, const int* in_sizes, int n_in,
                              void* d_out, int out_size, void* d_ws, size_t ws_size,
                              hipStream_t stream) {
    const float* x  = (const float*)d_in[0];
    const int*   ei = (const int*)d_in[1];
    const float* ew = (const float*)d_in[2];
    const float* Wm = (const float*)d_in[3];
    const float* bv = (const float*)d_in[4];
    float* out = (float*)d_out;

    float* deg  = (float*)d_ws;                       // B*N
    float* aggx = deg + (size_t)BATCH * NNODE;        // B*N*F_IN

    // 1) init deg=1, aggx=0 (ws is re-poisoned before every call)
    {
        int total = BATCH * NNODE * F_IN;   // covers both arrays' extents
        k_init<<<(total + 255) / 256, 256, 0, stream>>>(deg, aggx);
    }
    // 2) degree accumulation
    {
        dim3 grid((NEDGE + 255) / 256, BATCH);
        k_deg<<<grid, 256, 0, stream>>>(ei, ew, deg);
    }
    // 3) dinv = rsqrt(deg)
    k_rsqrt<<<(BATCH * NNODE + 255) / 256, 256, 0, stream>>>(deg);
    // 4) edge scatter in F_IN space
    {
        dim3 grid((NEDGE + 255) / 256, BATCH);
        k_scatter<<<grid, 256, 0, stream>>>(ei, ew, x, deg, aggx);
    }
    // 5) finalize: +self loop, @W+b, transposed store
    k_final<<<(BATCH * NNODE + 255) / 256, 256, 0, stream>>>(aggx, x, deg, Wm, bv, out);
}

// Round 4
// 1140.004 us; speedup vs baseline: 3.7861x; 3.7861x over previous
//
#include <hip/hip_runtime.h>

// Problem constants (from reference setup_inputs)
#define BATCH 4
#define NNODE 50000
#define NEDGE 1600000
#define NBIN (BATCH * NNODE)                     // 200000 bins (b,dst)
#define SCAN_BLK 1024
#define NSCANBLK ((NBIN + SCAN_BLK) / SCAN_BLK)  // 196 (covers NBIN+1 element)
#define CNT_PAD (NSCANBLK * SCAN_BLK)            // 200704
#define F_IN 12
#define F_OUT 48
#define SEQ 12

// ---------------- CSR build ----------------

__global__ void __launch_bounds__(256) k_zero(int* __restrict__ cnt) {
    int i = blockIdx.x * 256 + threadIdx.x;
    if (i < CNT_PAD) cnt[i] = 0;
}

__global__ void __launch_bounds__(256) k_count(const int* __restrict__ ei,
                                               int* __restrict__ cnt) {
    int e = blockIdx.x * 256 + threadIdx.x;
    int b = blockIdx.y;
    if (e >= NEDGE) return;
    int dst = ei[((size_t)b * 2 + 1) * NEDGE + e];
    atomicAdd(&cnt[b * NNODE + dst], 1);
}

// Block-level exclusive scan: 256 threads x 4 elements = 1024 per block.
__global__ void __launch_bounds__(256) k_scan1(const int* __restrict__ cnt,
                                               int* __restrict__ off,
                                               int* __restrict__ bsum) {
    __shared__ int w[256];
    int t = threadIdx.x;
    int base = blockIdx.x * SCAN_BLK;
    int4 v = ((const int4*)(cnt + base))[t];
    int lsum = v.x + v.y + v.z + v.w;
    w[t] = lsum;
    __syncthreads();
    // Hillis-Steele inclusive scan over 256 partials
    for (int d = 1; d < 256; d <<= 1) {
        int val = (t >= d) ? w[t - d] : 0;
        __syncthreads();
        w[t] += val;
        __syncthreads();
    }
    int excl = w[t] - lsum;
    int4 o;
    o.x = excl;
    o.y = excl + v.x;
    o.z = excl + v.x + v.y;
    o.w = excl + v.x + v.y + v.z;
    ((int4*)(off + base))[t] = o;
    if (t == 255) bsum[blockIdx.x] = w[255];
}

__global__ void __launch_bounds__(256) k_scan2(const int* __restrict__ bsum,
                                               int* __restrict__ bscan) {
    __shared__ int w[256];
    int t = threadIdx.x;
    int v = (t < NSCANBLK) ? bsum[t] : 0;
    w[t] = v;
    __syncthreads();
    for (int d = 1; d < 256; d <<= 1) {
        int val = (t >= d) ? w[t - d] : 0;
        __syncthreads();
        w[t] += val;
        __syncthreads();
    }
    if (t < NSCANBLK) bscan[t] = w[t] - v;   // exclusive
}

__global__ void __launch_bounds__(256) k_scan3(int* __restrict__ off,
                                               const int* __restrict__ bscan,
                                               int* __restrict__ cur) {
    int i = blockIdx.x * 256 + threadIdx.x;
    if (i <= NBIN) {
        int o = off[i] + bscan[i / SCAN_BLK];
        off[i] = o;
        if (i < NBIN) cur[i] = o;
    }
}

__global__ void __launch_bounds__(256) k_fill(const int* __restrict__ ei,
                                              const float* __restrict__ ew,
                                              int* __restrict__ cur,
                                              int2* __restrict__ rec) {
    int e = blockIdx.x * 256 + threadIdx.x;
    int b = blockIdx.y;
    if (e >= NEDGE) return;
    const size_t ebase = (size_t)b * 2 * NEDGE;
    int src = ei[ebase + e];
    int dst = ei[ebase + NEDGE + e];
    float w = ew[(size_t)b * NEDGE + e];
    int pos = atomicAdd(&cur[b * NNODE + dst], 1);
    rec[pos] = make_int2(src, __float_as_int(w));
}

// ---------------- numeric phase (atomic-free) ----------------

__global__ void __launch_bounds__(256) k_deg(const int* __restrict__ off,
                                             const int2* __restrict__ rec,
                                             float* __restrict__ dinv) {
    int i = blockIdx.x * 256 + threadIdx.x;
    if (i >= NBIN) return;
    int s = off[i], epos = off[i + 1];
    float d = 1.0f;                      // self-loop weight
    for (int j = s; j < epos; j++) d += __int_as_float(rec[j].y);
    dinv[i] = rsqrtf(d);
}

// Gather messages + self loop + W,b + transposed store, all in one pass.
__global__ void __launch_bounds__(256) k_gather_final(const int* __restrict__ off,
                                                      const int2* __restrict__ rec,
                                                      const float* __restrict__ x,
                                                      const float* __restrict__ dinv,
                                                      const float* __restrict__ Wm,
                                                      const float* __restrict__ bias,
                                                      float* __restrict__ out) {
    __shared__ float sW[F_IN * F_OUT];
    __shared__ float sb[F_OUT];
    int t = threadIdx.x;
    for (int i = t; i < F_IN * F_OUT; i += 256) sW[i] = Wm[i];
    if (t < F_OUT) sb[t] = bias[t];
    __syncthreads();

    int i = blockIdx.x * 256 + t;
    if (i >= NBIN) return;
    int b = i / NNODE;
    int n = i - b * NNODE;

    float di = dinv[i];
    const float* xr = x + (size_t)i * F_IN;

    // a = S + di*x  (later scaled by di:  out_feat = di*S + di^2*x)
    float a[F_IN];
#pragma unroll
    for (int k = 0; k < F_IN; k++) a[k] = di * xr[k];

    const float* dv = dinv + b * NNODE;
    const float* xb = x + (size_t)b * NNODE * F_IN;
    int s = off[i], epos = off[i + 1];
    for (int j = s; j < epos; j++) {
        int2 r = rec[j];
        int src = r.x;
        float c = __int_as_float(r.y) * dv[src];
        const float4* x4 = (const float4*)(xb + (size_t)src * F_IN);
        float4 v0 = x4[0], v1 = x4[1], v2 = x4[2];
        a[0] += c * v0.x;  a[1] += c * v0.y;  a[2]  += c * v0.z;  a[3]  += c * v0.w;
        a[4] += c * v1.x;  a[5] += c * v1.y;  a[6]  += c * v1.z;  a[7]  += c * v1.w;
        a[8] += c * v2.x;  a[9] += c * v2.y;  a[10] += c * v2.z;  a[11] += c * v2.w;
    }
#pragma unroll
    for (int k = 0; k < F_IN; k++) a[k] *= di;

    float h[F_OUT];
#pragma unroll
    for (int j = 0; j < F_OUT; j++) {
        float acc = sb[j];
#pragma unroll
        for (int k = 0; k < F_IN; k++) acc = fmaf(a[k], sW[k * F_OUT + j], acc);
        h[j] = acc;
    }

    float4* out4 = (float4*)out;
#pragma unroll
    for (int sq = 0; sq < SEQ; sq++) {
        float4 v = make_float4(h[sq * 4 + 0], h[sq * 4 + 1], h[sq * 4 + 2], h[sq * 4 + 3]);
        out4[(size_t)(b * SEQ + sq) * NNODE + n] = v;
    }
}

extern "C" void kernel_launch(void* const* d_in, const int* in_sizes, int n_in,
                              void* d_out, int out_size, void* d_ws, size_t ws_size,
                              hipStream_t stream) {
    const float* x  = (const float*)d_in[0];
    const int*   ei = (const int*)d_in[1];
    const float* ew = (const float*)d_in[2];
    const float* Wm = (const float*)d_in[3];
    const float* bv = (const float*)d_in[4];
    float* out = (float*)d_out;

    // Workspace layout (rec first for 8B alignment): ~54.5 MB total
    int2* rec   = (int2*)d_ws;                           // B*E int2   (51.2 MB)
    int*  cnt   = (int*)(rec + (size_t)BATCH * NEDGE);   // CNT_PAD
    int*  off   = cnt + CNT_PAD;                         // CNT_PAD (uses NBIN+1)
    int*  cur   = off + CNT_PAD;                         // NBIN
    int*  bsum  = cur + NBIN;                            // NSCANBLK
    int*  bscan = bsum + NSCANBLK;                       // NSCANBLK
    float* dinv = (float*)(bscan + NSCANBLK);            // NBIN

    // 1) histogram of edges per (b,dst)
    k_zero<<<(CNT_PAD + 255) / 256, 256, 0, stream>>>(cnt);
    {
        dim3 grid((NEDGE + 255) / 256, BATCH);
        k_count<<<grid, 256, 0, stream>>>(ei, cnt);
    }
    // 2) exclusive scan -> bin offsets (+cursor snapshot)
    k_scan1<<<NSCANBLK, 256, 0, stream>>>(cnt, off, bsum);
    k_scan2<<<1, 256, 0, stream>>>(bsum, bscan);
    k_scan3<<<(NBIN + 256) / 256, 256, 0, stream>>>(off, bscan, cur);
    // 3) place {src, ew} records into dst bins
    {
        dim3 grid((NEDGE + 255) / 256, BATCH);
        k_fill<<<grid, 256, 0, stream>>>(ei, ew, cur, rec);
    }
    // 4) degree -> dinv (contiguous, atomic-free)
    k_deg<<<(NBIN + 255) / 256, 256, 0, stream>>>(off, rec, dinv);
    // 5) gather + self-loop + W,b + transposed store
    k_gather_final<<<(NBIN + 255) / 256, 256, 0, stream>>>(off, rec, x, dinv, Wm, bv, out);
}

// Round 5
// 674.327 us; speedup vs baseline: 6.4006x; 1.6906x over previous
//
#include <hip/hip_runtime.h>

// Problem constants
#define BATCH 4
#define NNODE 50000
#define NEDGE 1600000
#define F_IN 12
#define F_OUT 48
#define SEQ 12

#define BNODE 128                               // dst-nodes per bucket (pow2)
#define NBUCK ((NNODE + BNODE - 1) / BNODE)     // 391 buckets per batch
#define NBINS (BATCH * NBUCK)                   // 1564
#define SCAN_N 2048                             // padded for single-block scan
#define EBLK 4096                               // edges per count/fill block
#define EPB (EBLK / 256)                        // 16 edges per thread
#define NFB ((NEDGE + EBLK - 1) / EBLK)         // 391 blocks per batch

// ---------- CSR build: two-level bucketing ----------

__global__ void __launch_bounds__(256) k_zero(int* __restrict__ cnt) {
    int i = blockIdx.x * 256 + threadIdx.x;
    if (i < SCAN_N) cnt[i] = 0;
}

// Per-block LDS histogram over 391 buckets, one global atomic per (block,bucket).
__global__ void __launch_bounds__(256) k_count(const int* __restrict__ ei,
                                               int* __restrict__ cnt) {
    __shared__ int h[NBUCK];
    int t = threadIdx.x;
    for (int i = t; i < NBUCK; i += 256) h[i] = 0;
    __syncthreads();
    int b = blockIdx.y;
    int e0 = blockIdx.x * EBLK;
    const int* dsts = ei + ((size_t)b * 2 + 1) * NEDGE;
    for (int it = 0; it < EPB; ++it) {
        int e = e0 + it * 256 + t;
        if (e < NEDGE) atomicAdd(&h[dsts[e] >> 7], 1);
    }
    __syncthreads();
    for (int i = t; i < NBUCK; i += 256) {
        int c = h[i];
        if (c) atomicAdd(&cnt[b * NBUCK + i], c);
    }
}

// Single-block exclusive scan of 2048 (>= NBINS+1) bin counts; snapshot cursors.
__global__ void __launch_bounds__(256) k_scan(const int* __restrict__ cnt,
                                              int* __restrict__ off,
                                              int* __restrict__ cur) {
    __shared__ int w[256];
    int t = threadIdx.x;
    int base = t * 8;
    int loc[8];
    int s = 0;
#pragma unroll
    for (int j = 0; j < 8; j++) { loc[j] = cnt[base + j]; s += loc[j]; }
    w[t] = s;
    __syncthreads();
    for (int d = 1; d < 256; d <<= 1) {
        int v = (t >= d) ? w[t - d] : 0;
        __syncthreads();
        w[t] += v;
        __syncthreads();
    }
    int run = w[t] - s;   // exclusive prefix of this thread's chunk
#pragma unroll
    for (int j = 0; j < 8; j++) {
        int i = base + j;
        off[i] = run;
        if (i < NBINS) cur[i] = run;
        run += loc[j];
    }
}

// Rank in LDS, reserve per-(block,bucket) segments, LDS-reorder, coalesced copy-out.
__global__ void __launch_bounds__(256) k_fill(const int* __restrict__ ei,
                                              const float* __restrict__ ew,
                                              int* __restrict__ cur,
                                              int2* __restrict__ rec) {
    __shared__ int h[512];          // bucket counts (padded to 512)
    __shared__ int loff[512];       // local exclusive offsets
    __shared__ int gbase[NBUCK];    // global base per bucket
    __shared__ int2 srec[EBLK];     // reordered records (32 KB)
    __shared__ short sbuck[EBLK];   // bucket id per slot (8 KB)
    __shared__ int w[256];

    int t = threadIdx.x;
    int b = blockIdx.y;
    int e0 = blockIdx.x * EBLK;
    for (int i = t; i < 512; i += 256) h[i] = 0;
    __syncthreads();

    const size_t ebase = (size_t)b * 2 * NEDGE;
    const int* srcs = ei + ebase;
    const int* dsts = ei + ebase + NEDGE;
    const float* ws = ew + (size_t)b * NEDGE;

    int2 myrec[EPB];
    int mypk[EPB];
#pragma unroll
    for (int it = 0; it < EPB; ++it) {
        int e = e0 + it * 256 + t;
        int valid = e < NEDGE;
        int src = 0, dst = 0;
        float wv = 0.0f;
        if (valid) { src = srcs[e]; dst = dsts[e]; wv = ws[e]; }
        int g = dst >> 7;
        int r = 0;
        if (valid) r = atomicAdd(&h[g], 1);
        myrec[it] = make_int2(((dst & (BNODE - 1)) << 16) | src, __float_as_int(wv));
        mypk[it] = valid ? ((g << 16) | r) : -1;
    }
    __syncthreads();

    // block-level exclusive scan over 512 bucket counts (2 per thread)
    int c0 = h[2 * t], c1 = h[2 * t + 1];
    int ls = c0 + c1;
    w[t] = ls;
    __syncthreads();
    for (int d = 1; d < 256; d <<= 1) {
        int v = (t >= d) ? w[t - d] : 0;
        __syncthreads();
        w[t] += v;
        __syncthreads();
    }
    int excl = w[t] - ls;
    loff[2 * t] = excl;
    loff[2 * t + 1] = excl + c0;
    __syncthreads();

    // reserve global space: one atomic per non-empty (block,bucket)
    for (int i = t; i < NBUCK; i += 256) {
        int c = h[i];
        if (c) gbase[i] = atomicAdd(&cur[b * NBUCK + i], c);
    }
    // stage records ordered by (bucket, rank)
#pragma unroll
    for (int it = 0; it < EPB; ++it) {
        int pk = mypk[it];
        if (pk >= 0) {
            int g = pk >> 16, r = pk & 0xFFFF;
            int p = loff[g] + r;
            srec[p] = myrec[it];
            sbuck[p] = (short)g;
        }
    }
    __syncthreads();

    // coalesced copy-out: consecutive slots share bucket -> contiguous global
    int nvalid = min(EBLK, NEDGE - e0);
    for (int j = t; j < nvalid; j += 256) {
        int g = sbuck[j];
        rec[gbase[g] + (j - loff[g])] = srec[j];
    }
}

// ---------- numeric phase (bucket-local, atomic-free at global) ----------

__global__ void __launch_bounds__(256) k_deg(const int* __restrict__ off,
                                             const int2* __restrict__ rec,
                                             float* __restrict__ dinv) {
    __shared__ float sdeg[BNODE];
    int t = threadIdx.x;
    int bin = blockIdx.x;
    int b = bin / NBUCK, g = bin - b * NBUCK;
    if (t < BNODE) sdeg[t] = 1.0f;           // self-loop weight
    __syncthreads();
    int s = off[bin], e = off[bin + 1];
    for (int j = s + t; j < e; j += 256)
        atomicAdd(&sdeg[rec[j].x >> 16], __int_as_float(rec[j].y));
    __syncthreads();
    int n0 = g * BNODE;
    if (t < BNODE) {
        int n = n0 + t;
        if (n < NNODE) dinv[b * NNODE + n] = rsqrtf(sdeg[t]);
    }
}

__global__ void __launch_bounds__(256) k_gather(const int* __restrict__ off,
                                                const int2* __restrict__ rec,
                                                const float* __restrict__ x,
                                                const float* __restrict__ dinv,
                                                const float* __restrict__ Wm,
                                                const float* __restrict__ bias,
                                                float* __restrict__ out) {
    __shared__ float acc[BNODE * F_IN];      // 6 KB message accumulators
    __shared__ float sW[F_IN * F_OUT];
    __shared__ float sb[F_OUT];
    int t = threadIdx.x;
    for (int i = t; i < BNODE * F_IN; i += 256) acc[i] = 0.0f;
    for (int i = t; i < F_IN * F_OUT; i += 256) sW[i] = Wm[i];
    if (t < F_OUT) sb[t] = bias[t];
    __syncthreads();

    int bin = blockIdx.x;
    int b = bin / NBUCK, g = bin - b * NBUCK;
    const float* dv = dinv + b * NNODE;
    const float* xb = x + (size_t)b * NNODE * F_IN;

    int s = off[bin], e = off[bin + 1];
    for (int j = s + t; j < e; j += 256) {
        int2 r = rec[j];
        int node = r.x >> 16;
        int src = r.x & 0xFFFF;
        float c = __int_as_float(r.y) * dv[src];
        const float4* x4 = (const float4*)(xb + (size_t)src * F_IN);
        float4 v0 = x4[0], v1 = x4[1], v2 = x4[2];
        float* a = acc + node * F_IN;
        atomicAdd(a + 0,  c * v0.x);
        atomicAdd(a + 1,  c * v0.y);
        atomicAdd(a + 2,  c * v0.z);
        atomicAdd(a + 3,  c * v0.w);
        atomicAdd(a + 4,  c * v1.x);
        atomicAdd(a + 5,  c * v1.y);
        atomicAdd(a + 6,  c * v1.z);
        atomicAdd(a + 7,  c * v1.w);
        atomicAdd(a + 8,  c * v2.x);
        atomicAdd(a + 9,  c * v2.y);
        atomicAdd(a + 10, c * v2.z);
        atomicAdd(a + 11, c * v2.w);
    }
    __syncthreads();

    // finalize: 2 threads per node, 24 outputs each; transposed coalesced store
    int node = t >> 1, half = t & 1;
    int n = g * BNODE + node;
    if (n >= NNODE) return;
    float di = dv[n];
    const float4* x4 = (const float4*)(xb + (size_t)n * F_IN);
    float4 v0 = x4[0], v1 = x4[1], v2 = x4[2];
    float xr[F_IN] = {v0.x, v0.y, v0.z, v0.w, v1.x, v1.y, v1.z, v1.w,
                      v2.x, v2.y, v2.z, v2.w};
    float a[F_IN];
#pragma unroll
    for (int k = 0; k < F_IN; k++)
        a[k] = di * acc[node * F_IN + k] + di * di * xr[k];

    float h[24];
#pragma unroll
    for (int j = 0; j < 24; j++) {
        int jj = half * 24 + j;
        float v = sb[jj];
#pragma unroll
        for (int k = 0; k < F_IN; k++) v = fmaf(a[k], sW[k * F_OUT + jj], v);
        h[j] = v;
    }
    float4* out4 = (float4*)out;
#pragma unroll
    for (int q = 0; q < 6; q++) {
        int s_idx = half * 6 + q;
        out4[(size_t)(b * SEQ + s_idx) * NNODE + n] =
            make_float4(h[q * 4 + 0], h[q * 4 + 1], h[q * 4 + 2], h[q * 4 + 3]);
    }
}

extern "C" void kernel_launch(void* const* d_in, const int* in_sizes, int n_in,
                              void* d_out, int out_size, void* d_ws, size_t ws_size,
                              hipStream_t stream) {
    const float* x  = (const float*)d_in[0];
    const int*   ei = (const int*)d_in[1];
    const float* ew = (const float*)d_in[2];
    const float* Wm = (const float*)d_in[3];
    const float* bv = (const float*)d_in[4];
    float* out = (float*)d_out;

    // Workspace: rec (51.2MB) | cnt | off | cur | dinv  (~52MB total)
    int2* rec  = (int2*)d_ws;
    int*  cnt  = (int*)(rec + (size_t)BATCH * NEDGE);
    int*  off  = cnt + SCAN_N;
    int*  cur  = off + SCAN_N;
    float* dinv = (float*)(cur + NBINS);

    k_zero<<<SCAN_N / 256, 256, 0, stream>>>(cnt);
    {
        dim3 grid(NFB, BATCH);
        k_count<<<grid, 256, 0, stream>>>(ei, cnt);
    }
    k_scan<<<1, 256, 0, stream>>>(cnt, off, cur);
    {
        dim3 grid(NFB, BATCH);
        k_fill<<<grid, 256, 0, stream>>>(ei, ew, cur, rec);
    }
    k_deg<<<NBINS, 256, 0, stream>>>(off, rec, dinv);
    k_gather<<<NBINS, 256, 0, stream>>>(off, rec, x, dinv, Wm, bv, out);
}